// Round 2
// baseline (4767.835 us; speedup 1.0000x reference)
//
#include <hip/hip_runtime.h>

// ---------------------------------------------------------------------------
// 2-layer LSTM (B=64, T=256, D=512, H1=H2=1024) + dense head.
// R2: same 257-superstep pipeline as R1, but workspace shrunk 78MiB -> 46MiB.
// R1 post-mortem: seq1 full history (32MiB) pushed carve total past ws_size;
// OOB writes corrupted the harness's pristine input copies (call 1 passed,
// everything after deterministically wrong). Fix: h1 as a 2-parity ring.
//   - transpose-convert all weights fp32[K][N] -> bf16[N][K] (MFMA B layout)
//   - blocks 0..127 = layer1 step t=s, blocks 128..255 = layer2 step t=s-1
//     (wavefront pipeline; kernel boundary is the global barrier)
//   - 16x16x32 bf16 MFMA, fp32 accum, fp32 cell state, bf16 h.
// ---------------------------------------------------------------------------

typedef __bf16 bf16x8 __attribute__((ext_vector_type(8)));
typedef float f32x4 __attribute__((ext_vector_type(4)));

__device__ __forceinline__ unsigned short f2bf(float f) {
  unsigned u = __float_as_uint(f);
  unsigned r = (u + 0x7FFFu + ((u >> 16) & 1u)) >> 16;  // RNE (finite inputs)
  return (unsigned short)r;
}

// in: fp32 [R][C] row-major  ->  out: bf16 [C][R] row-major (i.e. B^T layout)
__global__ __launch_bounds__(256) void transpose_to_bf16(
    const float* __restrict__ in, unsigned short* __restrict__ out, int R, int C) {
  __shared__ float tile[32][33];
  int tx = threadIdx.x & 31, ty = threadIdx.x >> 5;  // 32 x 8
  int c0 = blockIdx.x * 32, r0 = blockIdx.y * 32;
#pragma unroll
  for (int i = 0; i < 4; ++i)
    tile[ty + i * 8][tx] = in[(size_t)(r0 + ty + i * 8) * C + (c0 + tx)];
  __syncthreads();
#pragma unroll
  for (int i = 0; i < 4; ++i)
    out[(size_t)(c0 + ty + i * 8) * R + (r0 + tx)] = f2bf(tile[tx][ty + i * 8]);
}

__global__ __launch_bounds__(256) void convert_to_bf16(
    const float* __restrict__ in, unsigned short* __restrict__ out, int n4) {
  int i = blockIdx.x * 256 + threadIdx.x;
  if (i >= n4) return;
  float4 v = reinterpret_cast<const float4*>(in)[i];
  ushort4 o;
  o.x = f2bf(v.x); o.y = f2bf(v.y); o.z = f2bf(v.z); o.w = f2bf(v.w);
  reinterpret_cast<ushort4*>(out)[i] = o;
}

// One pipelined superstep.
// blocks 0..127:  layer1, t = s      (128 = 64 unit-blocks x 2 batch-halves)
// blocks 128..255: layer2, t = s - 1
// Each block: M=32 batches, 16 units (4 gate tiles of N=16), K-chunks of 512.
// h1ring/h2ring: [2][64][1024] bf16 parity rings (write t&1, read (t-1)&1).
__global__ __launch_bounds__(256) void lstm_step(
    int s,
    const unsigned short* __restrict__ xbf,   // [64*256][512] bf16
    const unsigned short* __restrict__ W1t,   // [4096][512]
    const unsigned short* __restrict__ U1t,   // [4096][1024]
    const float* __restrict__ b1,             // [4096]
    const unsigned short* __restrict__ W2t,   // [4096][1024]
    const unsigned short* __restrict__ U2t,   // [4096][1024]
    const float* __restrict__ b2,             // [4096]
    unsigned short* __restrict__ h1ring,      // [2][64][1024] bf16
    unsigned short* __restrict__ h2ring,      // [2][64][1024] bf16
    float* __restrict__ c1,                   // [64][1024] fp32
    float* __restrict__ c2)                   // [64][1024] fp32
{
  __shared__ __align__(16) unsigned short Alds[32][520];  // 512 + 8 pad (banks)
  __shared__ float Zlds[32][68];                          // z exchange

  const int bid = blockIdx.x;
  const bool is2 = bid >= 128;
  const int lb = is2 ? bid - 128 : bid;
  const int ub = lb >> 1;      // unit block 0..63
  const int mg = lb & 1;       // batch half
  const int u0 = ub * 16;
  const int t = is2 ? (s - 1) : s;
  if (t < 0 || t >= 256) return;   // idle edge blocks (uniform exit)

  const int tid  = threadIdx.x;
  const int wave = tid >> 6;       // wave g handles gate g (i,f,g,o)
  const int lane = tid & 63;
  const int quad = lane >> 4;
  const int l16  = lane & 15;

  const int nchunks = is2 ? 4 : 3;          // K = 2048 / 1536
  const int col = wave * 1024 + u0 + l16;   // column in [0,4096)

  f32x4 acc0 = {0.f, 0.f, 0.f, 0.f};  // batches 0..15 of this half
  f32x4 acc1 = {0.f, 0.f, 0.f, 0.f};  // batches 16..31

  const int srow = tid >> 3;  // staging: 32 rows x 8 threads/row
  const int l8   = tid & 7;
  const int b_s  = mg * 32 + srow;

  for (int ch = 0; ch < nchunks; ++ch) {
    // A-source for this 512-wide K chunk (nullptr => zero state => skip chunk)
    const unsigned short* src = nullptr;
    if (!is2) {
      if (ch == 0)      src = xbf + ((size_t)(b_s * 256 + t)) * 512;
      else if (t > 0)   src = h1ring + (size_t)((t - 1) & 1) * 64 * 1024 + (size_t)b_s * 1024 + (ch - 1) * 512;
    } else {
      if (ch < 2)       src = h1ring + (size_t)(t & 1) * 64 * 1024 + (size_t)b_s * 1024 + ch * 512;
      else if (t > 0)   src = h2ring + (size_t)((t - 1) & 1) * 64 * 1024 + (size_t)b_s * 1024 + (ch - 2) * 512;
    }
    if (src == nullptr) continue;  // trailing chunks only; block-uniform branch

    __syncthreads();  // protect Alds overwrite vs previous chunk's readers
#pragma unroll
    for (int j = 0; j < 8; ++j) {
      int kc = l8 + j * 8;  // 0..63 (16B chunks per row)
      uint4 v = *reinterpret_cast<const uint4*>(src + kc * 8);
      *reinterpret_cast<uint4*>(&Alds[srow][kc * 8]) = v;
    }
    __syncthreads();

    // B (weight) base for this wave's gate column strip, this chunk
    const unsigned short* bp;
    if (!is2) {
      if (ch == 0) bp = W1t + (size_t)col * 512;
      else         bp = U1t + (size_t)col * 1024 + (ch - 1) * 512;
    } else {
      if (ch < 2)  bp = W2t + (size_t)col * 1024 + ch * 512;
      else         bp = U2t + (size_t)col * 1024 + (ch - 2) * 512;
    }
    bp += quad * 8;

#pragma unroll
    for (int ks = 0; ks < 16; ++ks) {
      bf16x8 bfrag = *reinterpret_cast<const bf16x8*>(bp + ks * 32);
      bf16x8 a0 = *reinterpret_cast<const bf16x8*>(&Alds[l16][ks * 32 + quad * 8]);
      bf16x8 a1 = *reinterpret_cast<const bf16x8*>(&Alds[16 + l16][ks * 32 + quad * 8]);
      acc0 = __builtin_amdgcn_mfma_f32_16x16x32_bf16(a0, bfrag, acc0, 0, 0, 0);
      acc1 = __builtin_amdgcn_mfma_f32_16x16x32_bf16(a1, bfrag, acc1, 0, 0, 0);
    }
  }

  // exchange z across waves (gates live in different waves)
#pragma unroll
  for (int i = 0; i < 4; ++i) {
    Zlds[quad * 4 + i][wave * 16 + l16]      = acc0[i];
    Zlds[16 + quad * 4 + i][wave * 16 + l16] = acc1[i];
  }
  __syncthreads();

  const float* bias = is2 ? b2 : b1;
  float* cst = is2 ? c2 : c1;
  unsigned short* hring = is2 ? h2ring : h1ring;
  const bool first = (t == 0);  // zero initial state (ws is poisoned, not zeroed)
#pragma unroll
  for (int r = 0; r < 2; ++r) {
    int e = tid + r * 256;        // 512 (m,u) pairs
    int m = e >> 4, u = e & 15;
    int b = mg * 32 + m;
    int cu = u0 + u;
    float zi = Zlds[m][u]      + bias[cu];
    float zf = Zlds[m][16 + u] + bias[1024 + cu];
    float zg = Zlds[m][32 + u] + bias[2048 + cu];
    float zo = Zlds[m][48 + u] + bias[3072 + cu];
    float cold = first ? 0.f : cst[b * 1024 + cu];
    float ig = 1.f / (1.f + __expf(-zi));
    float fg = 1.f / (1.f + __expf(-zf));
    float gg = 1.f - 2.f / (1.f + __expf(2.f * zg));   // tanh
    float og = 1.f / (1.f + __expf(-zo));
    float cnew = fg * cold + ig * gg;
    cst[b * 1024 + cu] = cnew;
    float h = og * (1.f - 2.f / (1.f + __expf(2.f * cnew)));
    hring[(size_t)(t & 1) * 64 * 1024 + (size_t)b * 1024 + cu] = f2bf(h);
  }
}

// out[64][512] = h2_last @ Wd + bd.  One wave per 16x16 tile, K=1024.
__global__ __launch_bounds__(64) void dense_kernel(
    const unsigned short* __restrict__ h2,   // [64][1024] bf16
    const unsigned short* __restrict__ Wdt,  // [512][1024] bf16
    const float* __restrict__ bd,
    float* __restrict__ out) {
  int mt = blockIdx.x >> 5;  // 0..3
  int nt = blockIdx.x & 31;  // 0..31
  int lane = threadIdx.x;
  int quad = lane >> 4, l16 = lane & 15;
  f32x4 acc = {0.f, 0.f, 0.f, 0.f};
  const unsigned short* ap = h2 + (size_t)(mt * 16 + l16) * 1024 + quad * 8;
  const unsigned short* bp = Wdt + (size_t)(nt * 16 + l16) * 1024 + quad * 8;
#pragma unroll
  for (int ks = 0; ks < 32; ++ks) {
    bf16x8 a = *reinterpret_cast<const bf16x8*>(ap + ks * 32);
    bf16x8 b = *reinterpret_cast<const bf16x8*>(bp + ks * 32);
    acc = __builtin_amdgcn_mfma_f32_16x16x32_bf16(a, b, acc, 0, 0, 0);
  }
  int colo = nt * 16 + l16;
  float bias = bd[colo];
#pragma unroll
  for (int i = 0; i < 4; ++i)
    out[(size_t)(mt * 16 + quad * 4 + i) * 512 + colo] = acc[i] + bias;
}

extern "C" void kernel_launch(void* const* d_in, const int* in_sizes, int n_in,
                              void* d_out, int out_size, void* d_ws, size_t ws_size,
                              hipStream_t stream) {
  const float* x  = (const float*)d_in[0];
  const float* W1 = (const float*)d_in[1];
  const float* U1 = (const float*)d_in[2];
  const float* b1 = (const float*)d_in[3];
  const float* W2 = (const float*)d_in[4];
  const float* U2 = (const float*)d_in[5];
  const float* b2 = (const float*)d_in[6];
  const float* Wd = (const float*)d_in[7];
  const float* bd = (const float*)d_in[8];
  float* out = (float*)d_out;

  char* p = (char*)d_ws;
  auto carve = [&](size_t bytes) -> char* {
    char* r = p;
    p += (bytes + 255) & ~(size_t)255;
    return r;
  };
  // Total carve: 4+8+8+8+1+16 MiB (weights+x) + 4*256 KiB (rings+cell) ~= 46 MiB
  unsigned short* W1t  = (unsigned short*)carve((size_t)4096 * 512 * 2);
  unsigned short* U1t  = (unsigned short*)carve((size_t)4096 * 1024 * 2);
  unsigned short* W2t  = (unsigned short*)carve((size_t)4096 * 1024 * 2);
  unsigned short* U2t  = (unsigned short*)carve((size_t)4096 * 1024 * 2);
  unsigned short* Wdt  = (unsigned short*)carve((size_t)512 * 1024 * 2);
  unsigned short* xbf  = (unsigned short*)carve((size_t)64 * 256 * 512 * 2);
  unsigned short* h1r  = (unsigned short*)carve((size_t)2 * 64 * 1024 * 2);
  unsigned short* h2r  = (unsigned short*)carve((size_t)2 * 64 * 1024 * 2);
  float* c1 = (float*)carve((size_t)64 * 1024 * 4);
  float* c2 = (float*)carve((size_t)64 * 1024 * 4);
  (void)ws_size; (void)in_sizes; (void)n_in; (void)out_size;

  transpose_to_bf16<<<dim3(128, 16), 256, 0, stream>>>(W1, W1t, 512, 4096);
  transpose_to_bf16<<<dim3(128, 32), 256, 0, stream>>>(U1, U1t, 1024, 4096);
  transpose_to_bf16<<<dim3(128, 32), 256, 0, stream>>>(W2, W2t, 1024, 4096);
  transpose_to_bf16<<<dim3(128, 32), 256, 0, stream>>>(U2, U2t, 1024, 4096);
  transpose_to_bf16<<<dim3(16, 32), 256, 0, stream>>>(Wd, Wdt, 1024, 512);
  convert_to_bf16<<<8192, 256, 0, stream>>>(x, xbf, 64 * 256 * 512 / 4);

  for (int s = 0; s <= 256; ++s)
    lstm_step<<<256, 256, 0, stream>>>(s, xbf, W1t, U1t, b1, W2t, U2t, b2,
                                       h1r, h2r, c1, c2);

  dense_kernel<<<128, 64, 0, stream>>>(h2r + 64 * 1024, Wdt, bd, out);
}